// Round 2
// baseline (4924.254 us; speedup 1.0000x reference)
//
#include <hip/hip_runtime.h>
#include <stdint.h>
#include <stddef.h>

#define B_ 2
#define T_ 2048
#define C_ 1024
#define H_ 16
#define N_ 64
#define M_ (B_*T_)

__device__ __forceinline__ uint16_t f2bf(float x){
  uint32_t u = __float_as_uint(x);
  u += 0x7fffu + ((u >> 16) & 1u);   // RNE to bf16 (inputs finite)
  return (uint16_t)(u >> 16);
}
__device__ __forceinline__ float bf2f(uint32_t hu){
  return __uint_as_float(hu << 16);
}

// ---------------- f32 tiled GEMM ----------------
// C[i][j] = sum_k Aprep[i][k] * Bmat[j][k]   (b_nn==0, both row-major, dot along contiguous K)
//         = sum_k Aprep[i][k] * Bmat[k][j]   (b_nn==1)
// mode 0: Aprep = Amat
// mode 1: Aprep = x + (prev - x)*coef, prev = (t==0 ? 0 : x[i-1])   [token shift]
// mode 2: Aprep = Amat + Aaux*coef
__global__ __launch_bounds__(256, 2) void gemm_kernel(
    const float* __restrict__ Amat, int lda,
    const float* __restrict__ Aaux,
    const float* __restrict__ coef,
    int mode,
    const float* __restrict__ Bmat, int ldb, int b_nn,
    const float* __restrict__ resid,
    float* __restrict__ Cmat, int ldc,
    int K)
{
  __shared__ __align__(16) float As[16][132];
  __shared__ __align__(16) float Bs[16][132];
  const int tid = threadIdx.x;
  const int i0 = blockIdx.y * 128;
  const int j0 = blockIdx.x * 128;
  const int tx = tid & 15;
  const int ty = tid >> 4;

  float acc[8][8];
#pragma unroll
  for (int r=0;r<8;r++)
#pragma unroll
    for (int c=0;c<8;c++) acc[r][c] = 0.f;

  for (int k0 = 0; k0 < K; k0 += 16){
    if (tid < 128){
      const int i = i0 + tid;
      const float* ap = Amat + (size_t)i*lda + k0;
      float4 ta[4];
#pragma unroll
      for (int f=0;f<4;f++) ta[f] = *(const float4*)(ap + 4*f);
      if (mode == 1){
        const int t = i & (T_-1);
        const float* pp = ap - lda;
#pragma unroll
        for (int f=0;f<4;f++){
          float4 cf = *(const float4*)(coef + k0 + 4*f);
          float4 pv = {0.f,0.f,0.f,0.f};
          if (t > 0) pv = *(const float4*)(pp + 4*f);
          ta[f].x += (pv.x - ta[f].x)*cf.x;
          ta[f].y += (pv.y - ta[f].y)*cf.y;
          ta[f].z += (pv.z - ta[f].z)*cf.z;
          ta[f].w += (pv.w - ta[f].w)*cf.w;
        }
      } else if (mode == 2){
        const float* xp = Aaux + (size_t)i*lda + k0;
#pragma unroll
        for (int f=0;f<4;f++){
          float4 cf = *(const float4*)(coef + k0 + 4*f);
          float4 av = *(const float4*)(xp + 4*f);
          ta[f].x = fmaf(av.x, cf.x, ta[f].x);
          ta[f].y = fmaf(av.y, cf.y, ta[f].y);
          ta[f].z = fmaf(av.z, cf.z, ta[f].z);
          ta[f].w = fmaf(av.w, cf.w, ta[f].w);
        }
      }
#pragma unroll
      for (int f=0;f<4;f++){
        As[4*f+0][tid] = ta[f].x;
        As[4*f+1][tid] = ta[f].y;
        As[4*f+2][tid] = ta[f].z;
        As[4*f+3][tid] = ta[f].w;
      }
    } else {
      const int q = tid - 128;
      if (!b_nn){
        const float* bp = Bmat + (size_t)(j0+q)*ldb + k0;
        float4 tb[4];
#pragma unroll
        for (int f=0;f<4;f++) tb[f] = *(const float4*)(bp + 4*f);
#pragma unroll
        for (int f=0;f<4;f++){
          Bs[4*f+0][q] = tb[f].x;
          Bs[4*f+1][q] = tb[f].y;
          Bs[4*f+2][q] = tb[f].z;
          Bs[4*f+3][q] = tb[f].w;
        }
      } else {
#pragma unroll
        for (int s=0;s<4;s++){
          int f = q*4 + s;
          int kk = f >> 5;
          int j4 = f & 31;
          float4 wv = *(const float4*)(Bmat + (size_t)(k0+kk)*ldb + j0 + j4*4);
          *(float4*)&Bs[kk][j4*4] = wv;
        }
      }
    }
    __syncthreads();
#pragma unroll
    for (int kk=0;kk<16;kk++){
      float4 a0v = *(const float4*)&As[kk][ty*8];
      float4 a1v = *(const float4*)&As[kk][ty*8+4];
      float4 b0v = *(const float4*)&Bs[kk][tx*8];
      float4 b1v = *(const float4*)&Bs[kk][tx*8+4];
      float ar[8] = {a0v.x,a0v.y,a0v.z,a0v.w,a1v.x,a1v.y,a1v.z,a1v.w};
      float br[8] = {b0v.x,b0v.y,b0v.z,b0v.w,b1v.x,b1v.y,b1v.z,b1v.w};
#pragma unroll
      for (int r=0;r<8;r++)
#pragma unroll
        for (int c=0;c<8;c++) acc[r][c] = fmaf(ar[r], br[c], acc[r][c]);
    }
    __syncthreads();
  }

#pragma unroll
  for (int r=0;r<8;r++){
    const int i = i0 + ty*8 + r;
    float* cp = Cmat + (size_t)i*ldc + j0 + tx*8;
    float4 o0 = {acc[r][0],acc[r][1],acc[r][2],acc[r][3]};
    float4 o1 = {acc[r][4],acc[r][5],acc[r][6],acc[r][7]};
    if (resid){
      const float* rp = resid + (size_t)i*ldc + j0 + tx*8;
      float4 r0 = *(const float4*)rp;
      float4 r1 = *(const float4*)(rp+4);
      o0.x+=r0.x; o0.y+=r0.y; o0.z+=r0.z; o0.w+=r0.w;
      o1.x+=r1.x; o1.y+=r1.y; o1.z+=r1.z; o1.w+=r1.w;
    }
    *(float4*)cp = o0;
    *(float4*)(cp+4) = o1;
  }
}

// ---------------- fused elementwise + head norms + bf16 pack ----------------
// one wave per (token, head); lane = channel within head
__global__ __launch_bounds__(256) void fuse_kernel(
    const float* __restrict__ qm, const float* __restrict__ km,
    const float* __restrict__ vm, const float* __restrict__ vfm,
    const float* __restrict__ del, const float* __restrict__ x,
    const float* __restrict__ w0, const float* __restrict__ v0,
    const float* __restrict__ a0,
    uint32_t* __restrict__ packed, float* __restrict__ gout,
    float* __restrict__ ratio)
{
  const int lane = threadIdx.x & 63;
  const int ht = blockIdx.x*4 + (threadIdx.x >> 6);   // token*H + head
  const int i = ht >> 4;
  const int h = ht & 15;
  const int c = h*64 + lane;
  const size_t ic = (size_t)i*C_ + c;
  float qv = qm[ic], kv = km[ic], vv = vm[ic], vfv = vfm[ic], xv = x[ic];
  const size_t d0 = (size_t)i*4*C_ + c;
  float wd = del[d0], vd = del[d0+C_], ad = del[d0+2*C_], gd = del[d0+3*C_];

  // log_w = -exp(-softplus(-(w0+wd)) - 0.5)
  float z1 = -(w0[c]+wd);
  float sp = fmaxf(z1, 0.f) + log1pf(expf(-fabsf(z1)));
  float logw = -expf(-sp - 0.5f);
  float sv = 1.f/(1.f+expf(-(v0[c]+vd)));
  vv = vv + (vfv - vv)*sv;               // blend toward v_first
  float gv = 1.f + gd;
  float av = 1.f/(1.f+expf(-(a0[c]+ad)));

  uint16_t vr_u = f2bf(vv);
  float vrf = bf2f(vr_u);                // vnorm uses the bf16-rounded v (matches ref)

  float ksq = kv*kv, xsq = xv*xv, vsq = vrf*vrf;
#pragma unroll
  for (int off=32; off>0; off>>=1){
    ksq += __shfl_xor(ksq, off, 64);
    xsq += __shfl_xor(xsq, off, 64);
    vsq += __shfl_xor(vsq, off, 64);
  }
  float kn = sqrtf(ksq);
  float kkn = kv / fmaxf(kn, 1e-12f);
  float k2 = kv*av;
  float zv = -kkn;
  float bv = kkn*av;

  uint32_t p0 = (uint32_t)f2bf(logw) | ((uint32_t)f2bf(zv) << 16);
  uint32_t p1 = (uint32_t)f2bf(bv)   | ((uint32_t)f2bf(k2) << 16);
  uint32_t p2 = (uint32_t)f2bf(qv)   | ((uint32_t)vr_u << 16);
  uint32_t* pb = packed + ((size_t)ht*64 + lane)*3;
  pb[0]=p0; pb[1]=p1; pb[2]=p2;
  gout[ic] = gv;
  if (lane == 0)
    ratio[ht] = 1.f - sqrtf(xsq)/(sqrtf(vsq)+1e-12f);
}

// ---------------- sequential RWKV7 scan ----------------
// one wave per (b,h); thread = v-row; S[64] in VGPRs; j-vectors via LDS broadcast.
// S_t = S_{t-1}*diag(ew) + (S_{t-1} z) b^T + v k^T ; o = S_t q
__global__ __launch_bounds__(64) void scan_kernel(
    const uint32_t* __restrict__ packed, const float* __restrict__ ratio,
    const float* __restrict__ g, const float* __restrict__ rk,
    float* __restrict__ y)
{
  const int bh = blockIdx.x;
  const int b = bh / H_, h = bh % H_;
  const int lane = threadIdx.x;
  float S[N_];
#pragma unroll
  for (int j=0;j<N_;j++) S[j] = 0.f;
  const float sigrk = 1.f/(1.f+__expf(-rk[h*N_+lane]));
  __shared__ __align__(16) float ew_s[N_];
  __shared__ __align__(16) float z_s[N_];
  __shared__ __align__(16) float b_s[N_];
  __shared__ __align__(16) float k_s[N_];
  __shared__ __align__(16) float q_s[N_];

  // prefetch t = 0
  size_t ht = (size_t)(b*T_)*H_ + h;
  const uint32_t* pp = packed + (ht*64 + lane)*3;
  uint32_t u0 = pp[0], u1 = pp[1], u2 = pp[2];
  float uvn = ratio[ht];
  float gvn = g[(size_t)(b*T_)*C_ + h*N_ + lane];

  for (int t=0; t<T_; t++){
    const float wv = bf2f(u0 & 0xffffu);
    const float zv = bf2f(u0 >> 16);
    const float bv = bf2f(u1 & 0xffffu);
    const float kv = bf2f(u1 >> 16);
    const float qv = bf2f(u2 & 0xffffu);
    const float vt = bf2f(u2 >> 16);
    const float uv = uvn, gv = gvn;
    ew_s[lane] = __expf(wv);
    z_s[lane] = zv; b_s[lane] = bv; k_s[lane] = kv; q_s[lane] = qv;
    __syncthreads();
    if (t+1 < T_){   // software prefetch of next step's operands (hides HBM/L2 latency)
      size_t ht2 = (size_t)(b*T_ + t+1)*H_ + h;
      const uint32_t* p2 = packed + (ht2*64 + lane)*3;
      u0 = p2[0]; u1 = p2[1]; u2 = p2[2];
      uvn = ratio[ht2];
      gvn = g[(size_t)(b*T_ + t+1)*C_ + h*N_ + lane];
    }
    float sa = 0.f;
#pragma unroll
    for (int j4=0;j4<16;j4++){
      const float4 z4 = *(const float4*)&z_s[4*j4];
      sa = fmaf(S[4*j4+0], z4.x, sa);
      sa = fmaf(S[4*j4+1], z4.y, sa);
      sa = fmaf(S[4*j4+2], z4.z, sa);
      sa = fmaf(S[4*j4+3], z4.w, sa);
    }
    float o = 0.f;
#pragma unroll
    for (int j4=0;j4<16;j4++){
      const float4 e4 = *(const float4*)&ew_s[4*j4];
      const float4 b4 = *(const float4*)&b_s[4*j4];
      const float4 k4 = *(const float4*)&k_s[4*j4];
      const float4 q4 = *(const float4*)&q_s[4*j4];
      float s;
      s = fmaf(S[4*j4+0], e4.x, fmaf(sa, b4.x, vt*k4.x)); o = fmaf(s, q4.x, o); S[4*j4+0] = s;
      s = fmaf(S[4*j4+1], e4.y, fmaf(sa, b4.y, vt*k4.y)); o = fmaf(s, q4.y, o); S[4*j4+1] = s;
      s = fmaf(S[4*j4+2], e4.z, fmaf(sa, b4.z, vt*k4.z)); o = fmaf(s, q4.z, o); S[4*j4+2] = s;
      s = fmaf(S[4*j4+3], e4.w, fmaf(sa, b4.w, vt*k4.w)); o = fmaf(s, q4.w, o); S[4*j4+3] = s;
    }
    __syncthreads();
    const size_t oc = (size_t)(b*T_ + t)*C_ + h*N_ + lane;
    y[oc] = (o*0.125f + vt*uv*sigrk)*gv;   // 0.125 = N^-0.5 ; u = ratio*sigmoid(r_k); then *g
  }
}

extern "C" void kernel_launch(void* const* d_in, const int* in_sizes, int n_in,
                              void* d_out, int out_size, void* d_ws, size_t ws_size,
                              hipStream_t stream)
{
  const float* residual = (const float*)d_in[0];
  const float* x    = (const float*)d_in[1];
  const float* x0   = (const float*)d_in[2];
  const float* dx0  = (const float*)d_in[3];
  const float* Wq   = (const float*)d_in[4];
  const float* Wk   = (const float*)d_in[5];
  const float* Wv   = (const float*)d_in[6];
  const float* Wpr  = (const float*)d_in[7];
  const float* x_q  = (const float*)d_in[8];
  const float* x_k  = (const float*)d_in[9];
  const float* x_v  = (const float*)d_in[10];
  const float* v0   = (const float*)d_in[11];
  const float* w0   = (const float*)d_in[12];
  const float* a0   = (const float*)d_in[13];
  const float* miss = (const float*)d_in[14];
  const float* rk   = (const float*)d_in[15];
  float* out = (float*)d_out;

  char* ws = (char*)d_ws;
  const size_t SZ = (size_t)M_*C_*sizeof(float);       // 16 MiB
  float* q_m   = (float*)(ws + 0*SZ);
  float* k_m   = (float*)(ws + 1*SZ);
  float* v_m   = (float*)(ws + 2*SZ);
  float* vf_m  = (float*)(ws + 3*SZ);
  float* del   = (float*)(ws + 4*SZ);                  // 4*SZ bytes
  uint32_t* packed = (uint32_t*)(ws + 8*SZ);           // 3*SZ bytes
  float* g_m   = (float*)(ws + 11*SZ);                 // SZ
  float* ratio = (float*)(ws + 12*SZ);                 // M_*H_*4
  float* y_m   = (float*)(ws + 0*SZ);                  // overlays q_m (dead after fuse)

  dim3 blk(256);
  dim3 grdC(C_/128, M_/128);
  dim3 grdD(4*C_/128, M_/128);
  // q,k,v with token-shift prep fused into the A-tile load
  gemm_kernel<<<grdC, blk, 0, stream>>>(x,  C_, nullptr, x_q, 1, Wq,  C_,   0, nullptr, q_m,  C_,   C_);
  gemm_kernel<<<grdC, blk, 0, stream>>>(x,  C_, nullptr, x_k, 1, Wk,  C_,   0, nullptr, k_m,  C_,   C_);
  gemm_kernel<<<grdC, blk, 0, stream>>>(x,  C_, nullptr, x_v, 1, Wv,  C_,   0, nullptr, v_m,  C_,   C_);
  // v_first = (x0 + dx0*x_v) @ Wv^T
  gemm_kernel<<<grdC, blk, 0, stream>>>(x0, C_, dx0,     x_v, 2, Wv,  C_,   0, nullptr, vf_m, C_,   C_);
  // deltas = x[:, :128] @ miss   (NN layout)
  gemm_kernel<<<grdD, blk, 0, stream>>>(x,  C_, nullptr, nullptr, 0, miss, 4*C_, 1, nullptr, del, 4*C_, 128);
  fuse_kernel<<<M_*H_/4, blk, 0, stream>>>(q_m, k_m, v_m, vf_m, del, x, w0, v0, a0, packed, g_m, ratio);
  scan_kernel<<<B_*H_, 64, 0, stream>>>(packed, ratio, g_m, rk, y_m);
  // out = residual + y @ Wproj^T
  gemm_kernel<<<grdC, blk, 0, stream>>>(y_m, C_, nullptr, nullptr, 0, Wpr, C_, 0, residual, out, C_, C_);
}

// Round 3
// 1310.628 us; speedup vs baseline: 3.7572x; 3.7572x over previous
//
#include <hip/hip_runtime.h>
#include <stdint.h>
#include <stddef.h>

#define B_ 2
#define T_ 2048
#define C_ 1024
#define H_ 16
#define N_ 64
#define M_ (B_*T_)
#define L_ 128              // chunk length
#define NC_ (T_/L_)         // 16 chunks

__device__ __forceinline__ uint16_t f2bf(float x){
  uint32_t u = __float_as_uint(x);
  u += 0x7fffu + ((u >> 16) & 1u);   // RNE to bf16 (inputs finite)
  return (uint16_t)(u >> 16);
}
__device__ __forceinline__ float bf2f(uint32_t hu){
  return __uint_as_float(hu << 16);
}

// ---------------- f32 tiled GEMM ----------------
// C[i][j] = sum_k Aprep[i][k] * Bmat[j][k]   (b_nn==0)
//         = sum_k Aprep[i][k] * Bmat[k][j]   (b_nn==1)
// mode 0: Aprep = Amat ; mode 1: token-shift mix ; mode 2: Amat + Aaux*coef
__global__ __launch_bounds__(256, 2) void gemm_kernel(
    const float* __restrict__ Amat, int lda,
    const float* __restrict__ Aaux,
    const float* __restrict__ coef,
    int mode,
    const float* __restrict__ Bmat, int ldb, int b_nn,
    const float* __restrict__ resid,
    float* __restrict__ Cmat, int ldc,
    int K)
{
  __shared__ __align__(16) float As[16][132];
  __shared__ __align__(16) float Bs[16][132];
  const int tid = threadIdx.x;
  const int i0 = blockIdx.y * 128;
  const int j0 = blockIdx.x * 128;
  const int tx = tid & 15;
  const int ty = tid >> 4;

  float acc[8][8];
#pragma unroll
  for (int r=0;r<8;r++)
#pragma unroll
    for (int c=0;c<8;c++) acc[r][c] = 0.f;

  for (int k0 = 0; k0 < K; k0 += 16){
    if (tid < 128){
      const int i = i0 + tid;
      const float* ap = Amat + (size_t)i*lda + k0;
      float4 ta[4];
#pragma unroll
      for (int f=0;f<4;f++) ta[f] = *(const float4*)(ap + 4*f);
      if (mode == 1){
        const int t = i & (T_-1);
        const float* pp = ap - lda;
#pragma unroll
        for (int f=0;f<4;f++){
          float4 cf = *(const float4*)(coef + k0 + 4*f);
          float4 pv = {0.f,0.f,0.f,0.f};
          if (t > 0) pv = *(const float4*)(pp + 4*f);
          ta[f].x += (pv.x - ta[f].x)*cf.x;
          ta[f].y += (pv.y - ta[f].y)*cf.y;
          ta[f].z += (pv.z - ta[f].z)*cf.z;
          ta[f].w += (pv.w - ta[f].w)*cf.w;
        }
      } else if (mode == 2){
        const float* xp = Aaux + (size_t)i*lda + k0;
#pragma unroll
        for (int f=0;f<4;f++){
          float4 cf = *(const float4*)(coef + k0 + 4*f);
          float4 av = *(const float4*)(xp + 4*f);
          ta[f].x = fmaf(av.x, cf.x, ta[f].x);
          ta[f].y = fmaf(av.y, cf.y, ta[f].y);
          ta[f].z = fmaf(av.z, cf.z, ta[f].z);
          ta[f].w = fmaf(av.w, cf.w, ta[f].w);
        }
      }
#pragma unroll
      for (int f=0;f<4;f++){
        As[4*f+0][tid] = ta[f].x;
        As[4*f+1][tid] = ta[f].y;
        As[4*f+2][tid] = ta[f].z;
        As[4*f+3][tid] = ta[f].w;
      }
    } else {
      const int q = tid - 128;
      if (!b_nn){
        const float* bp = Bmat + (size_t)(j0+q)*ldb + k0;
        float4 tb[4];
#pragma unroll
        for (int f=0;f<4;f++) tb[f] = *(const float4*)(bp + 4*f);
#pragma unroll
        for (int f=0;f<4;f++){
          Bs[4*f+0][q] = tb[f].x;
          Bs[4*f+1][q] = tb[f].y;
          Bs[4*f+2][q] = tb[f].z;
          Bs[4*f+3][q] = tb[f].w;
        }
      } else {
#pragma unroll
        for (int s=0;s<4;s++){
          int f = q*4 + s;
          int kk = f >> 5;
          int j4 = f & 31;
          float4 wv = *(const float4*)(Bmat + (size_t)(k0+kk)*ldb + j0 + j4*4);
          *(float4*)&Bs[kk][j4*4] = wv;
        }
      }
    }
    __syncthreads();
#pragma unroll
    for (int kk=0;kk<16;kk++){
      float4 a0v = *(const float4*)&As[kk][ty*8];
      float4 a1v = *(const float4*)&As[kk][ty*8+4];
      float4 b0v = *(const float4*)&Bs[kk][tx*8];
      float4 b1v = *(const float4*)&Bs[kk][tx*8+4];
      float ar[8] = {a0v.x,a0v.y,a0v.z,a0v.w,a1v.x,a1v.y,a1v.z,a1v.w};
      float br[8] = {b0v.x,b0v.y,b0v.z,b0v.w,b1v.x,b1v.y,b1v.z,b1v.w};
#pragma unroll
      for (int r=0;r<8;r++)
#pragma unroll
        for (int c=0;c<8;c++) acc[r][c] = fmaf(ar[r], br[c], acc[r][c]);
    }
    __syncthreads();
  }

#pragma unroll
  for (int r=0;r<8;r++){
    const int i = i0 + ty*8 + r;
    float* cp = Cmat + (size_t)i*ldc + j0 + tx*8;
    float4 o0 = {acc[r][0],acc[r][1],acc[r][2],acc[r][3]};
    float4 o1 = {acc[r][4],acc[r][5],acc[r][6],acc[r][7]};
    if (resid){
      const float* rp = resid + (size_t)i*ldc + j0 + tx*8;
      float4 r0 = *(const float4*)rp;
      float4 r1 = *(const float4*)(rp+4);
      o0.x+=r0.x; o0.y+=r0.y; o0.z+=r0.z; o0.w+=r0.w;
      o1.x+=r1.x; o1.y+=r1.y; o1.z+=r1.z; o1.w+=r1.w;
    }
    *(float4*)cp = o0;
    *(float4*)(cp+4) = o1;
  }
}

// ---------------- fused elementwise + head norms + bf16 pack ----------------
__global__ __launch_bounds__(256) void fuse_kernel(
    const float* __restrict__ qm, const float* __restrict__ km,
    const float* __restrict__ vm, const float* __restrict__ vfm,
    const float* __restrict__ del, const float* __restrict__ x,
    const float* __restrict__ w0, const float* __restrict__ v0,
    const float* __restrict__ a0,
    uint32_t* __restrict__ packed, float* __restrict__ gout,
    float* __restrict__ ratio)
{
  const int lane = threadIdx.x & 63;
  const int ht = blockIdx.x*4 + (threadIdx.x >> 6);   // token*H + head
  const int i = ht >> 4;
  const int h = ht & 15;
  const int c = h*64 + lane;
  const size_t ic = (size_t)i*C_ + c;
  float qv = qm[ic], kv = km[ic], vv = vm[ic], vfv = vfm[ic], xv = x[ic];
  const size_t d0 = (size_t)i*4*C_ + c;
  float wd = del[d0], vd = del[d0+C_], ad = del[d0+2*C_], gd = del[d0+3*C_];

  float z1 = -(w0[c]+wd);
  float sp = fmaxf(z1, 0.f) + log1pf(expf(-fabsf(z1)));
  float logw = -expf(-sp - 0.5f);
  float sv = 1.f/(1.f+expf(-(v0[c]+vd)));
  vv = vv + (vfv - vv)*sv;
  float gv = 1.f + gd;
  float av = 1.f/(1.f+expf(-(a0[c]+ad)));

  uint16_t vr_u = f2bf(vv);
  float vrf = bf2f(vr_u);

  float ksq = kv*kv, xsq = xv*xv, vsq = vrf*vrf;
#pragma unroll
  for (int off=32; off>0; off>>=1){
    ksq += __shfl_xor(ksq, off, 64);
    xsq += __shfl_xor(xsq, off, 64);
    vsq += __shfl_xor(vsq, off, 64);
  }
  float kn = sqrtf(ksq);
  float kkn = kv / fmaxf(kn, 1e-12f);
  float k2 = kv*av;
  float zv = -kkn;
  float bv = kkn*av;

  uint32_t p0 = (uint32_t)f2bf(logw) | ((uint32_t)f2bf(zv) << 16);
  uint32_t p1 = (uint32_t)f2bf(bv)   | ((uint32_t)f2bf(k2) << 16);
  uint32_t p2 = (uint32_t)f2bf(qv)   | ((uint32_t)vr_u << 16);
  uint32_t* pb = packed + ((size_t)ht*64 + lane)*3;
  pb[0]=p0; pb[1]=p1; pb[2]=p2;
  gout[ic] = gv;
  if (lane == 0)
    ratio[ht] = 1.f - sqrtf(xsq)/(sqrtf(vsq)+1e-12f);
}

// ================= chunked scan =================
// Recurrence: S_t = S_{t-1}*M_t + v_t k_t^T,  M_t = diag(ew_t) + z_t b_t^T.
// Per chunk c: Phi_c = prod M_t (X from I), C_c = chunk scan from 0 (Z).
// Pass2: S_start(c+1) = S_start(c)*Phi_c + C_c (sequential, small matmul).
// Pass3: per chunk, rerun scan from S_start(c), emit outputs.

// ---- pass 1: per-chunk Phi + C. 256 thr: thread=(rp=tid>>2 row, qr=tid&3 k-quarter)
__global__ __launch_bounds__(256) void chunk_phi_kernel(
    const uint32_t* __restrict__ packed,
    float* __restrict__ phi, float* __restrict__ cc)
{
  const int blk = blockIdx.x;          // bh*NC_ + c
  const int c  = blk & (NC_-1);
  const int bh = blk >> 4;             // NC_ == 16
  const int b = bh >> 4, h = bh & 15;
  const int tid = threadIdx.x;
  const int rp = tid >> 2;
  const int qr = tid & 3;
  const int t0 = c * L_;

  __shared__ float ewS[4][N_], zS[4][N_], bS[4][N_], kS[4][N_], vS[4][N_];

  float X[16], Z[16];
#pragma unroll
  for (int i=0;i<16;i++){ X[i] = (qr*16+i == rp) ? 1.f : 0.f; Z[i] = 0.f; }

  const int s = tid >> 6, d = tid & 63;
  size_t ap = (((size_t)(b*T_+t0+s))*H_ + h)*64 + d;
  uint32_t pu0 = packed[ap*3], pu1 = packed[ap*3+1], pu2 = packed[ap*3+2];

  for (int tg = 0; tg < L_; tg += 4){
    __syncthreads();                      // prev group's readers done
    ewS[s][d] = __expf(bf2f(pu0 & 0xffffu));
    zS[s][d]  = bf2f(pu0 >> 16);
    bS[s][d]  = bf2f(pu1 & 0xffffu);
    kS[s][d]  = bf2f(pu1 >> 16);
    vS[s][d]  = bf2f(pu2 >> 16);
    if (tg + 4 < L_){
      size_t a2 = (((size_t)(b*T_+t0+tg+4+s))*H_ + h)*64 + d;
      pu0 = packed[a2*3]; pu1 = packed[a2*3+1]; pu2 = packed[a2*3+2];
    }
    __syncthreads();                      // group visible
#pragma unroll 1
    for (int ss=0; ss<4; ss++){
      float4 zv[4], ev[4], bv4[4], kv[4];
#pragma unroll
      for (int i4=0;i4<4;i4++){
        zv[i4]  = *(const float4*)&zS[ss][qr*16+i4*4];
        ev[i4]  = *(const float4*)&ewS[ss][qr*16+i4*4];
        bv4[i4] = *(const float4*)&bS[ss][qr*16+i4*4];
        kv[i4]  = *(const float4*)&kS[ss][qr*16+i4*4];
      }
      const float vr = vS[ss][rp];
      float a0=0.f,a1=0.f,a2=0.f,a3=0.f, c0=0.f,c1=0.f,c2=0.f,c3=0.f;
#pragma unroll
      for (int i4=0;i4<4;i4++){
        const float4 z4 = zv[i4];
        a0 = fmaf(X[i4*4+0], z4.x, a0); a1 = fmaf(X[i4*4+1], z4.y, a1);
        a2 = fmaf(X[i4*4+2], z4.z, a2); a3 = fmaf(X[i4*4+3], z4.w, a3);
        c0 = fmaf(Z[i4*4+0], z4.x, c0); c1 = fmaf(Z[i4*4+1], z4.y, c1);
        c2 = fmaf(Z[i4*4+2], z4.z, c2); c3 = fmaf(Z[i4*4+3], z4.w, c3);
      }
      float sx = (a0+a1)+(a2+a3);
      float sz = (c0+c1)+(c2+c3);
      sx += __shfl_xor(sx,1,64); sx += __shfl_xor(sx,2,64);
      sz += __shfl_xor(sz,1,64); sz += __shfl_xor(sz,2,64);
#pragma unroll
      for (int i4=0;i4<4;i4++){
        const float4 e4=ev[i4], b4=bv4[i4], k4=kv[i4];
        X[i4*4+0] = fmaf(X[i4*4+0], e4.x, sx*b4.x);
        X[i4*4+1] = fmaf(X[i4*4+1], e4.y, sx*b4.y);
        X[i4*4+2] = fmaf(X[i4*4+2], e4.z, sx*b4.z);
        X[i4*4+3] = fmaf(X[i4*4+3], e4.w, sx*b4.w);
        Z[i4*4+0] = fmaf(Z[i4*4+0], e4.x, fmaf(sz, b4.x, vr*k4.x));
        Z[i4*4+1] = fmaf(Z[i4*4+1], e4.y, fmaf(sz, b4.y, vr*k4.y));
        Z[i4*4+2] = fmaf(Z[i4*4+2], e4.z, fmaf(sz, b4.z, vr*k4.z));
        Z[i4*4+3] = fmaf(Z[i4*4+3], e4.w, fmaf(sz, b4.w, vr*k4.w));
      }
    }
  }
  const size_t base = (size_t)blk*4096 + (size_t)rp*64 + qr*16;
#pragma unroll
  for (int i4=0;i4<4;i4++){
    float4 xo = {X[i4*4+0],X[i4*4+1],X[i4*4+2],X[i4*4+3]};
    float4 zo = {Z[i4*4+0],Z[i4*4+1],Z[i4*4+2],Z[i4*4+3]};
    *(float4*)&phi[base + i4*4] = xo;
    *(float4*)&cc [base + i4*4] = zo;
  }
}

// ---- pass 2: sequential chunk combine per (b,h). 256 thr: (rb=tid>>4, cq=tid&15)
__global__ __launch_bounds__(256) void chunk_state_kernel(
    const float* __restrict__ phi, const float* __restrict__ cc,
    float* __restrict__ sstart)
{
  const int bh = blockIdx.x;
  const int tid = threadIdx.x;
  const int rb = tid >> 4;   // 0..15 -> rows rb+16m
  const int cq = tid & 15;   // cols cq*4..cq*4+3
  __shared__ float Sld[64][65];
  __shared__ float Fld[64][68];
  float acc[4][4];
#pragma unroll
  for (int m=0;m<4;m++)
#pragma unroll
    for (int i=0;i<4;i++) acc[m][i] = 0.f;
#pragma unroll
  for (int m=0;m<4;m++){
    float4 z4 = {0.f,0.f,0.f,0.f};
    *(float4*)&Sld[rb+16*m][cq*4] = z4;
  }
  const float* pc = phi + (size_t)bh*NC_*4096;
  float4 pf[4];
#pragma unroll
  for (int p=0;p<4;p++) pf[p] = *(const float4*)&pc[(size_t)p*1024 + tid*4];

  for (int c=0;c<NC_;c++){
    __syncthreads();                     // prev matmul done with Fld; Sld writes done
#pragma unroll
    for (int p=0;p<4;p++){
      int f = p*1024 + tid*4;
      *(float4*)&Fld[f>>6][f&63] = pf[p];
    }
    if (c+1 < NC_){
#pragma unroll
      for (int p=0;p<4;p++) pf[p] = *(const float4*)&pc[(size_t)(c+1)*4096 + p*1024 + tid*4];
    }
    float na[4][4];
#pragma unroll
    for (int m=0;m<4;m++){
      float4 ci = *(const float4*)&cc[(size_t)(bh*NC_+c)*4096 + (size_t)(rb+16*m)*64 + cq*4];
      na[m][0]=ci.x; na[m][1]=ci.y; na[m][2]=ci.z; na[m][3]=ci.w;
    }
    // store S_start(c) (= acc, state before this chunk)
#pragma unroll
    for (int m=0;m<4;m++){
      float4 so = {acc[m][0],acc[m][1],acc[m][2],acc[m][3]};
      *(float4*)&sstart[(size_t)(bh*NC_+c)*4096 + (size_t)(rb+16*m)*64 + cq*4] = so;
    }
    __syncthreads();                     // Fld (and Sld) visible
#pragma unroll 1
    for (int k0=0;k0<64;k0+=4){
      float4 sr[4];
#pragma unroll
      for (int m=0;m<4;m++) sr[m] = *(const float4*)&Sld[rb+16*m][k0];
      const float4 f0 = *(const float4*)&Fld[k0+0][cq*4];
      const float4 f1 = *(const float4*)&Fld[k0+1][cq*4];
      const float4 f2 = *(const float4*)&Fld[k0+2][cq*4];
      const float4 f3 = *(const float4*)&Fld[k0+3][cq*4];
#pragma unroll
      for (int m=0;m<4;m++){
        na[m][0] = fmaf(sr[m].x, f0.x, na[m][0]); na[m][0] = fmaf(sr[m].y, f1.x, na[m][0]);
        na[m][0] = fmaf(sr[m].z, f2.x, na[m][0]); na[m][0] = fmaf(sr[m].w, f3.x, na[m][0]);
        na[m][1] = fmaf(sr[m].x, f0.y, na[m][1]); na[m][1] = fmaf(sr[m].y, f1.y, na[m][1]);
        na[m][1] = fmaf(sr[m].z, f2.y, na[m][1]); na[m][1] = fmaf(sr[m].w, f3.y, na[m][1]);
        na[m][2] = fmaf(sr[m].x, f0.z, na[m][2]); na[m][2] = fmaf(sr[m].y, f1.z, na[m][2]);
        na[m][2] = fmaf(sr[m].z, f2.z, na[m][2]); na[m][2] = fmaf(sr[m].w, f3.z, na[m][2]);
        na[m][3] = fmaf(sr[m].x, f0.w, na[m][3]); na[m][3] = fmaf(sr[m].y, f1.w, na[m][3]);
        na[m][3] = fmaf(sr[m].z, f2.w, na[m][3]); na[m][3] = fmaf(sr[m].w, f3.w, na[m][3]);
      }
    }
    __syncthreads();                     // matmul's Sld reads done
#pragma unroll
    for (int m=0;m<4;m++){
      float4 so = {na[m][0],na[m][1],na[m][2],na[m][3]};
      *(float4*)&Sld[rb+16*m][cq*4] = so;
#pragma unroll
      for (int i=0;i<4;i++) acc[m][i] = na[m][i];
    }
  }
}

// ---- pass 3: per-chunk scan from S_start, emit y. 256 thr: (r=tid>>2, qr=tid&3)
__global__ __launch_bounds__(256) void chunk_out_kernel(
    const uint32_t* __restrict__ packed, const float* __restrict__ ratio,
    const float* __restrict__ g, const float* __restrict__ rk,
    const float* __restrict__ sstart, float* __restrict__ y)
{
  const int blk = blockIdx.x;
  const int c  = blk & (NC_-1);
  const int bh = blk >> 4;
  const int b = bh >> 4, h = bh & 15;
  const int tid = threadIdx.x;
  const int r  = tid >> 2;
  const int qr = tid & 3;
  const int t0 = c * L_;

  __shared__ float ewS[4][N_], zS[4][N_], bS[4][N_], kS[4][N_], qS[4][N_], vS[4][N_], gS[4][N_];
  __shared__ float ratS[4];

  float S[16];
#pragma unroll
  for (int i4=0;i4<4;i4++){
    float4 s4 = *(const float4*)&sstart[(size_t)blk*4096 + (size_t)r*64 + qr*16 + i4*4];
    S[i4*4+0]=s4.x; S[i4*4+1]=s4.y; S[i4*4+2]=s4.z; S[i4*4+3]=s4.w;
  }
  const float sigrk = 1.f/(1.f+__expf(-rk[h*64+r]));

  const int s = tid >> 6, d = tid & 63;
  size_t ap = (((size_t)(b*T_+t0+s))*H_ + h)*64 + d;
  uint32_t pu0 = packed[ap*3], pu1 = packed[ap*3+1], pu2 = packed[ap*3+2];
  float pg = g[(size_t)(b*T_+t0+s)*C_ + h*64 + d];
  float prat = 0.f;
  if (d == 0) prat = ratio[(size_t)(b*T_+t0+s)*H_ + h];

  for (int tg = 0; tg < L_; tg += 4){
    __syncthreads();
    ewS[s][d] = __expf(bf2f(pu0 & 0xffffu));
    zS[s][d]  = bf2f(pu0 >> 16);
    bS[s][d]  = bf2f(pu1 & 0xffffu);
    kS[s][d]  = bf2f(pu1 >> 16);
    qS[s][d]  = bf2f(pu2 & 0xffffu);
    vS[s][d]  = bf2f(pu2 >> 16);
    gS[s][d]  = pg;
    if (d == 0) ratS[s] = prat;
    if (tg + 4 < L_){
      size_t a2 = (((size_t)(b*T_+t0+tg+4+s))*H_ + h)*64 + d;
      pu0 = packed[a2*3]; pu1 = packed[a2*3+1]; pu2 = packed[a2*3+2];
      pg = g[(size_t)(b*T_+t0+tg+4+s)*C_ + h*64 + d];
      if (d == 0) prat = ratio[(size_t)(b*T_+t0+tg+4+s)*H_ + h];
    }
    __syncthreads();
#pragma unroll 1
    for (int ss=0; ss<4; ss++){
      float4 zv[4], ev[4], bv4[4], kv[4], qv[4];
#pragma unroll
      for (int i4=0;i4<4;i4++){
        zv[i4]  = *(const float4*)&zS[ss][qr*16+i4*4];
        ev[i4]  = *(const float4*)&ewS[ss][qr*16+i4*4];
        bv4[i4] = *(const float4*)&bS[ss][qr*16+i4*4];
        kv[i4]  = *(const float4*)&kS[ss][qr*16+i4*4];
        qv[i4]  = *(const float4*)&qS[ss][qr*16+i4*4];
      }
      const float vr = vS[ss][r];
      const float gvr = gS[ss][r];
      const float uv = ratS[ss];
      float a0=0.f,a1=0.f,a2=0.f,a3=0.f;
#pragma unroll
      for (int i4=0;i4<4;i4++){
        const float4 z4 = zv[i4];
        a0 = fmaf(S[i4*4+0], z4.x, a0); a1 = fmaf(S[i4*4+1], z4.y, a1);
        a2 = fmaf(S[i4*4+2], z4.z, a2); a3 = fmaf(S[i4*4+3], z4.w, a3);
      }
      float sa = (a0+a1)+(a2+a3);
      sa += __shfl_xor(sa,1,64); sa += __shfl_xor(sa,2,64);
      float p0=0.f,p1=0.f,p2=0.f,p3=0.f;
#pragma unroll
      for (int i4=0;i4<4;i4++){
        const float4 e4=ev[i4], b4=bv4[i4], k4=kv[i4], q4=qv[i4];
        float t;
        t = fmaf(S[i4*4+0], e4.x, fmaf(sa, b4.x, vr*k4.x)); S[i4*4+0]=t; p0 = fmaf(t, q4.x, p0);
        t = fmaf(S[i4*4+1], e4.y, fmaf(sa, b4.y, vr*k4.y)); S[i4*4+1]=t; p1 = fmaf(t, q4.y, p1);
        t = fmaf(S[i4*4+2], e4.z, fmaf(sa, b4.z, vr*k4.z)); S[i4*4+2]=t; p2 = fmaf(t, q4.z, p2);
        t = fmaf(S[i4*4+3], e4.w, fmaf(sa, b4.w, vr*k4.w)); S[i4*4+3]=t; p3 = fmaf(t, q4.w, p3);
      }
      float o = (p0+p1)+(p2+p3);
      o += __shfl_xor(o,1,64); o += __shfl_xor(o,2,64);
      if (qr == 0){
        y[(size_t)(b*T_+t0+tg+ss)*C_ + h*64 + r] = (o*0.125f + vr*uv*sigrk)*gvr;
      }
    }
  }
}

extern "C" void kernel_launch(void* const* d_in, const int* in_sizes, int n_in,
                              void* d_out, int out_size, void* d_ws, size_t ws_size,
                              hipStream_t stream)
{
  const float* residual = (const float*)d_in[0];
  const float* x    = (const float*)d_in[1];
  const float* x0   = (const float*)d_in[2];
  const float* dx0  = (const float*)d_in[3];
  const float* Wq   = (const float*)d_in[4];
  const float* Wk   = (const float*)d_in[5];
  const float* Wv   = (const float*)d_in[6];
  const float* Wpr  = (const float*)d_in[7];
  const float* x_q  = (const float*)d_in[8];
  const float* x_k  = (const float*)d_in[9];
  const float* x_v  = (const float*)d_in[10];
  const float* v0   = (const float*)d_in[11];
  const float* w0   = (const float*)d_in[12];
  const float* a0   = (const float*)d_in[13];
  const float* miss = (const float*)d_in[14];
  const float* rk   = (const float*)d_in[15];
  float* out = (float*)d_out;

  char* ws = (char*)d_ws;
  const size_t SZ = (size_t)M_*C_*sizeof(float);       // 16 MiB
  float* q_m   = (float*)(ws + 0*SZ);
  float* k_m   = (float*)(ws + 1*SZ);
  float* v_m   = (float*)(ws + 2*SZ);
  float* vf_m  = (float*)(ws + 3*SZ);
  float* del   = (float*)(ws + 4*SZ);                  // 64 MiB, dead after fuse
  uint32_t* packed = (uint32_t*)(ws + 8*SZ);           // 48 MiB
  float* g_m   = (float*)(ws + 11*SZ);                 // 16 MiB
  float* ratio = (float*)(ws + 12*SZ);                 // 256 KiB
  // chunked-scan scratch overlays the dead `del` region (24 MiB < 64 MiB):
  float* phi    = (float*)(ws + 4*SZ);                 // 8 MiB
  float* cc     = (float*)(ws + 4*SZ + (size_t)(8<<20));
  float* sstart = (float*)(ws + 4*SZ + (size_t)(16<<20));
  float* y_m   = (float*)(ws + 0*SZ);                  // overlays q_m (dead after fuse)

  dim3 blk(256);
  dim3 grdC(C_/128, M_/128);
  dim3 grdD(4*C_/128, M_/128);
  gemm_kernel<<<grdC, blk, 0, stream>>>(x,  C_, nullptr, x_q, 1, Wq,  C_,   0, nullptr, q_m,  C_,   C_);
  gemm_kernel<<<grdC, blk, 0, stream>>>(x,  C_, nullptr, x_k, 1, Wk,  C_,   0, nullptr, k_m,  C_,   C_);
  gemm_kernel<<<grdC, blk, 0, stream>>>(x,  C_, nullptr, x_v, 1, Wv,  C_,   0, nullptr, v_m,  C_,   C_);
  gemm_kernel<<<grdC, blk, 0, stream>>>(x0, C_, dx0,     x_v, 2, Wv,  C_,   0, nullptr, vf_m, C_,   C_);
  gemm_kernel<<<grdD, blk, 0, stream>>>(x,  C_, nullptr, nullptr, 0, miss, 4*C_, 1, nullptr, del, 4*C_, 128);
  fuse_kernel<<<M_*H_/4, blk, 0, stream>>>(q_m, k_m, v_m, vf_m, del, x, w0, v0, a0, packed, g_m, ratio);
  chunk_phi_kernel<<<B_*H_*NC_, blk, 0, stream>>>(packed, phi, cc);
  chunk_state_kernel<<<B_*H_, blk, 0, stream>>>(phi, cc, sstart);
  chunk_out_kernel<<<B_*H_*NC_, blk, 0, stream>>>(packed, ratio, g_m, rk, sstart, y_m);
  gemm_kernel<<<grdC, blk, 0, stream>>>(y_m, C_, nullptr, nullptr, 0, Wpr, C_, 0, residual, out, C_, C_);
}

// Round 4
// 531.011 us; speedup vs baseline: 9.2734x; 2.4682x over previous
//
#include <hip/hip_runtime.h>
#include <stdint.h>
#include <stddef.h>

#define B_ 2
#define T_ 2048
#define C_ 1024
#define H_ 16
#define N_ 64
#define M_ (B_*T_)
#define L_ 128              // chunk length
#define NC_ (T_/L_)         // 16 chunks

typedef unsigned short ushort_t;
typedef __attribute__((ext_vector_type(8))) __bf16 bf16x8;
typedef __attribute__((ext_vector_type(4))) float  f32x4;

__device__ __forceinline__ ushort_t f2bf(float x){
  uint32_t u = __float_as_uint(x);
  u += 0x7fffu + ((u >> 16) & 1u);   // RNE to bf16 (inputs finite)
  return (ushort_t)(u >> 16);
}
__device__ __forceinline__ float bf2f(uint32_t hu){
  return __uint_as_float(hu << 16);
}

// ---------------- prep: activations -> bf16 A-matrices ----------------
// Aq/Ak/Av = bf16(x + (prev - x)*coef)  (token shift, prev=0 at t==0)
// Axf = bf16(x0 + dx0*x_v) ; Xb = bf16(x)
__device__ __forceinline__ ushort4 mixq4(float4 a, float4 p, float4 c){
  ushort4 o;
  o.x = f2bf(fmaf(p.x - a.x, c.x, a.x));
  o.y = f2bf(fmaf(p.y - a.y, c.y, a.y));
  o.z = f2bf(fmaf(p.z - a.z, c.z, a.z));
  o.w = f2bf(fmaf(p.w - a.w, c.w, a.w));
  return o;
}
__global__ __launch_bounds__(256) void prep_act(
    const float* __restrict__ x, const float* __restrict__ x0,
    const float* __restrict__ dx0,
    const float* __restrict__ xq, const float* __restrict__ xk,
    const float* __restrict__ xv,
    ushort_t* __restrict__ Aq, ushort_t* __restrict__ Ak,
    ushort_t* __restrict__ Av, ushort_t* __restrict__ Axf,
    ushort_t* __restrict__ Xb)
{
  const int idx = blockIdx.x*256 + threadIdx.x;   // float4 index over M_*C_/4
  const int col4 = idx & 255;                     // C_/4 = 256
  const int i = idx >> 8;
  const int t = i & (T_-1);
  float4 a = ((const float4*)x)[idx];
  float4 p = {0.f,0.f,0.f,0.f};
  if (t > 0) p = ((const float4*)x)[idx - 256];
  float4 cq = ((const float4*)xq)[col4];
  float4 ck = ((const float4*)xk)[col4];
  float4 cv = ((const float4*)xv)[col4];
  ((ushort4*)Aq)[idx] = mixq4(a, p, cq);
  ((ushort4*)Ak)[idx] = mixq4(a, p, ck);
  ((ushort4*)Av)[idx] = mixq4(a, p, cv);
  float4 z = ((const float4*)x0)[idx];
  float4 d = ((const float4*)dx0)[idx];
  ushort4 of;
  of.x = f2bf(fmaf(d.x, cv.x, z.x));
  of.y = f2bf(fmaf(d.y, cv.y, z.y));
  of.z = f2bf(fmaf(d.z, cv.z, z.z));
  of.w = f2bf(fmaf(d.w, cv.w, z.w));
  ((ushort4*)Axf)[idx] = of;
  ushort4 ob = {f2bf(a.x), f2bf(a.y), f2bf(a.z), f2bf(a.w)};
  ((ushort4*)Xb)[idx] = ob;
}

// ---------------- prep: weights -> bf16 (slots q,k,v,v + proj) ----------------
__global__ __launch_bounds__(256) void prep_w(
    const float* __restrict__ Wq, const float* __restrict__ Wk,
    const float* __restrict__ Wv, const float* __restrict__ Wp,
    ushort_t* __restrict__ Wb, ushort_t* __restrict__ Wpb)
{
  const int y = blockIdx.y;
  const float* src = (y==0)?Wq:(y==1)?Wk:(y<4)?Wv:Wp;
  ushort_t* dst = (y<4) ? Wb + (size_t)y*C_*C_ : Wpb;
  const int idx = blockIdx.x*256 + threadIdx.x;   // float4 index over C_*C_/4
  float4 v = ((const float4*)src)[idx];
  ushort4 o = {f2bf(v.x), f2bf(v.y), f2bf(v.z), f2bf(v.w)};
  ((ushort4*)dst)[idx] = o;
}

// ---------------- prep: miss [128][4096] -> missT [4096][128] bf16 ----------------
__global__ __launch_bounds__(256) void prep_missT(
    const float* __restrict__ miss, ushort_t* __restrict__ missT)
{
  __shared__ ushort_t tile[128][66];
  const int j0 = blockIdx.x*64;
  const int tid = threadIdx.x;
#pragma unroll
  for (int rep=0; rep<8; rep++){
    int k = rep*16 + (tid>>4);
    int jj = (tid&15)*4;
    float4 v = *(const float4*)&miss[(size_t)k*4096 + j0 + jj];
    tile[k][jj+0]=f2bf(v.x); tile[k][jj+1]=f2bf(v.y);
    tile[k][jj+2]=f2bf(v.z); tile[k][jj+3]=f2bf(v.w);
  }
  __syncthreads();
#pragma unroll
  for (int rep=0; rep<8; rep++){
    int j = tid>>2;
    int kk = (tid&3)*32 + rep*4;
    ushort4 o = {tile[kk+0][j], tile[kk+1][j], tile[kk+2][j], tile[kk+3][j]};
    *(ushort4*)&missT[(size_t)(j0+j)*128 + kk] = o;
  }
}

// ---------------- bf16 MFMA GEMM (m97 structure) ----------------
// C[i][j] = sum_k A[i][k]*B[j][k]  (both bf16 row-major, K contiguous)
// 128x128 tile, BK=32, 4 waves x (4x4 16x16x32 mfma tiles), global_load_lds x16B.
__global__ __launch_bounds__(256, 2) void mfma_gemm(
    const ushort_t* __restrict__ Ab, int lda, int64_t Asz,
    const ushort_t* __restrict__ Bbp, int ldb, int64_t Bsz,
    void* __restrict__ Cb, int ldc, int64_t Csz, int c_bf16,
    const float* __restrict__ resid, int K)
{
  const ushort_t* A  = Ab  + (size_t)blockIdx.z * Asz;
  const ushort_t* Bm = Bbp + (size_t)blockIdx.z * Bsz;
  const int i0 = blockIdx.y * 128;
  const int j0 = blockIdx.x * 128;
  const int tid = threadIdx.x;
  const int lane = tid & 63;
  const int w = tid >> 6;
  const int wm = w & 1, wn = w >> 1;

  __shared__ ushort_t As[128*32];
  __shared__ ushort_t Bs[128*32];

  f32x4 acc[4][4];
#pragma unroll
  for (int i=0;i<4;i++)
#pragma unroll
    for (int j=0;j<4;j++) acc[i][j] = (f32x4){0.f,0.f,0.f,0.f};

  const int lr = lane >> 2;   // row within 16-row staging group
  const int ls = lane & 3;    // 16B segment (8 bf16)
  const ushort_t* ga = A  + (size_t)(i0 + w*32 + lr)*lda + ls*8;
  const ushort_t* gb = Bm + (size_t)(j0 + w*32 + lr)*ldb + ls*8;
  const int lm = lane & 15, lq = lane >> 4;

  for (int k0 = 0; k0 < K; k0 += 32){
    __syncthreads();
#pragma unroll
    for (int p=0;p<2;p++){
      __builtin_amdgcn_global_load_lds(
        (const __attribute__((address_space(1))) void*)(ga + (size_t)p*16*lda + k0),
        (__attribute__((address_space(3))) void*)&As[(w*32 + p*16)*32], 16, 0, 0);
      __builtin_amdgcn_global_load_lds(
        (const __attribute__((address_space(1))) void*)(gb + (size_t)p*16*ldb + k0),
        (__attribute__((address_space(3))) void*)&Bs[(w*32 + p*16)*32], 16, 0, 0);
    }
    __syncthreads();
    bf16x8 af[4], bfr[4];
#pragma unroll
    for (int i=0;i<4;i++)
      af[i] = *(const bf16x8*)&As[(wm*64 + i*16 + lm)*32 + lq*8];
#pragma unroll
    for (int j=0;j<4;j++)
      bfr[j] = *(const bf16x8*)&Bs[(wn*64 + j*16 + lm)*32 + lq*8];
#pragma unroll
    for (int i=0;i<4;i++)
#pragma unroll
      for (int j=0;j<4;j++)
        acc[i][j] = __builtin_amdgcn_mfma_f32_16x16x32_bf16(af[i], bfr[j], acc[i][j], 0, 0, 0);
  }

  // epilogue: D layout col=lane&15 (n), row=quad*4+reg (m)
  if (!c_bf16){
    float* C = (float*)Cb + (size_t)blockIdx.z * Csz;
#pragma unroll
    for (int i=0;i<4;i++)
#pragma unroll
      for (int j=0;j<4;j++)
#pragma unroll
        for (int r=0;r<4;r++){
          const int row = i0 + wm*64 + i*16 + lq*4 + r;
          const int col = j0 + wn*64 + j*16 + lm;
          float v = acc[i][j][r];
          if (resid) v += resid[(size_t)row*ldc + col];
          C[(size_t)row*ldc + col] = v;
        }
  } else {
    ushort_t* C = (ushort_t*)Cb + (size_t)blockIdx.z * Csz;
#pragma unroll
    for (int i=0;i<4;i++)
#pragma unroll
      for (int j=0;j<4;j++)
#pragma unroll
        for (int r=0;r<4;r++){
          const int row = i0 + wm*64 + i*16 + lq*4 + r;
          const int col = j0 + wn*64 + j*16 + lm;
          C[(size_t)row*ldc + col] = f2bf(acc[i][j][r]);
        }
  }
}

// ---------------- fused elementwise + head norms + bf16 pack ----------------
__global__ __launch_bounds__(256) void fuse_kernel(
    const float* __restrict__ qm, const float* __restrict__ km,
    const float* __restrict__ vm, const float* __restrict__ vfm,
    const ushort_t* __restrict__ del, const float* __restrict__ x,
    const float* __restrict__ w0, const float* __restrict__ v0,
    const float* __restrict__ a0,
    uint32_t* __restrict__ packed, float* __restrict__ gout,
    float* __restrict__ ratio)
{
  const int lane = threadIdx.x & 63;
  const int ht = blockIdx.x*4 + (threadIdx.x >> 6);   // token*H + head
  const int i = ht >> 4;
  const int h = ht & 15;
  const int c = h*64 + lane;
  const size_t ic = (size_t)i*C_ + c;
  float qv = qm[ic], kv = km[ic], vv = vm[ic], vfv = vfm[ic], xv = x[ic];
  const size_t d0 = (size_t)i*4*C_ + c;
  float wd = bf2f(del[d0]), vd = bf2f(del[d0+C_]);
  float ad = bf2f(del[d0+2*C_]), gd = bf2f(del[d0+3*C_]);

  float z1 = -(w0[c]+wd);
  float sp = fmaxf(z1, 0.f) + log1pf(expf(-fabsf(z1)));
  float logw = -expf(-sp - 0.5f);
  float sv = 1.f/(1.f+expf(-(v0[c]+vd)));
  vv = vv + (vfv - vv)*sv;
  float gv = 1.f + gd;
  float av = 1.f/(1.f+expf(-(a0[c]+ad)));

  ushort_t vr_u = f2bf(vv);
  float vrf = bf2f(vr_u);

  float ksq = kv*kv, xsq = xv*xv, vsq = vrf*vrf;
#pragma unroll
  for (int off=32; off>0; off>>=1){
    ksq += __shfl_xor(ksq, off, 64);
    xsq += __shfl_xor(xsq, off, 64);
    vsq += __shfl_xor(vsq, off, 64);
  }
  float kn = sqrtf(ksq);
  float kkn = kv / fmaxf(kn, 1e-12f);
  float k2 = kv*av;
  float zv = -kkn;
  float bv = kkn*av;

  uint32_t p0 = (uint32_t)f2bf(logw) | ((uint32_t)f2bf(zv) << 16);
  uint32_t p1 = (uint32_t)f2bf(bv)   | ((uint32_t)f2bf(k2) << 16);
  uint32_t p2 = (uint32_t)f2bf(qv)   | ((uint32_t)vr_u << 16);
  uint32_t* pb = packed + ((size_t)ht*64 + lane)*3;
  pb[0]=p0; pb[1]=p1; pb[2]=p2;
  gout[ic] = gv;
  if (lane == 0)
    ratio[ht] = 1.f - sqrtf(xsq)/(sqrtf(vsq)+1e-12f);
}

// ================= chunked scan =================
// S_t = S_{t-1}*M_t + v_t k_t^T,  M_t = diag(ew_t) + z_t b_t^T.

// ---- pass 1: per-chunk Phi + C
__global__ __launch_bounds__(256) void chunk_phi_kernel(
    const uint32_t* __restrict__ packed,
    float* __restrict__ phi, float* __restrict__ cc)
{
  const int blk = blockIdx.x;          // bh*NC_ + c
  const int c  = blk & (NC_-1);
  const int bh = blk >> 4;
  const int b = bh >> 4, h = bh & 15;
  const int tid = threadIdx.x;
  const int rp = tid >> 2;
  const int qr = tid & 3;
  const int t0 = c * L_;

  __shared__ float ewS[4][N_], zS[4][N_], bS[4][N_], kS[4][N_], vS[4][N_];

  float X[16], Z[16];
#pragma unroll
  for (int i=0;i<16;i++){ X[i] = (qr*16+i == rp) ? 1.f : 0.f; Z[i] = 0.f; }

  const int s = tid >> 6, d = tid & 63;
  size_t ap = (((size_t)(b*T_+t0+s))*H_ + h)*64 + d;
  uint32_t pu0 = packed[ap*3], pu1 = packed[ap*3+1], pu2 = packed[ap*3+2];

  for (int tg = 0; tg < L_; tg += 4){
    __syncthreads();
    ewS[s][d] = __expf(bf2f(pu0 & 0xffffu));
    zS[s][d]  = bf2f(pu0 >> 16);
    bS[s][d]  = bf2f(pu1 & 0xffffu);
    kS[s][d]  = bf2f(pu1 >> 16);
    vS[s][d]  = bf2f(pu2 >> 16);
    if (tg + 4 < L_){
      size_t a2 = (((size_t)(b*T_+t0+tg+4+s))*H_ + h)*64 + d;
      pu0 = packed[a2*3]; pu1 = packed[a2*3+1]; pu2 = packed[a2*3+2];
    }
    __syncthreads();
#pragma unroll 1
    for (int ss=0; ss<4; ss++){
      float4 zv[4], ev[4], bv4[4], kv[4];
#pragma unroll
      for (int i4=0;i4<4;i4++){
        zv[i4]  = *(const float4*)&zS[ss][qr*16+i4*4];
        ev[i4]  = *(const float4*)&ewS[ss][qr*16+i4*4];
        bv4[i4] = *(const float4*)&bS[ss][qr*16+i4*4];
        kv[i4]  = *(const float4*)&kS[ss][qr*16+i4*4];
      }
      const float vr = vS[ss][rp];
      float a0=0.f,a1=0.f,a2=0.f,a3=0.f, c0=0.f,c1=0.f,c2=0.f,c3=0.f;
#pragma unroll
      for (int i4=0;i4<4;i4++){
        const float4 z4 = zv[i4];
        a0 = fmaf(X[i4*4+0], z4.x, a0); a1 = fmaf(X[i4*4+1], z4.y, a1);
        a2 = fmaf(X[i4*4+2], z4.z, a2); a3 = fmaf(X[i4*4+3], z4.w, a3);
        c0 = fmaf(Z[i4*4+0], z4.x, c0); c1 = fmaf(Z[i4*4+1], z4.y, c1);
        c2 = fmaf(Z[i4*4+2], z4.z, c2); c3 = fmaf(Z[i4*4+3], z4.w, c3);
      }
      float sx = (a0+a1)+(a2+a3);
      float sz = (c0+c1)+(c2+c3);
      sx += __shfl_xor(sx,1,64); sx += __shfl_xor(sx,2,64);
      sz += __shfl_xor(sz,1,64); sz += __shfl_xor(sz,2,64);
#pragma unroll
      for (int i4=0;i4<4;i4++){
        const float4 e4=ev[i4], b4=bv4[i4], k4=kv[i4];
        X[i4*4+0] = fmaf(X[i4*4+0], e4.x, sx*b4.x);
        X[i4*4+1] = fmaf(X[i4*4+1], e4.y, sx*b4.y);
        X[i4*4+2] = fmaf(X[i4*4+2], e4.z, sx*b4.z);
        X[i4*4+3] = fmaf(X[i4*4+3], e4.w, sx*b4.w);
        Z[i4*4+0] = fmaf(Z[i4*4+0], e4.x, fmaf(sz, b4.x, vr*k4.x));
        Z[i4*4+1] = fmaf(Z[i4*4+1], e4.y, fmaf(sz, b4.y, vr*k4.y));
        Z[i4*4+2] = fmaf(Z[i4*4+2], e4.z, fmaf(sz, b4.z, vr*k4.z));
        Z[i4*4+3] = fmaf(Z[i4*4+3], e4.w, fmaf(sz, b4.w, vr*k4.w));
      }
    }
  }
  const size_t base = (size_t)blk*4096 + (size_t)rp*64 + qr*16;
#pragma unroll
  for (int i4=0;i4<4;i4++){
    float4 xo = {X[i4*4+0],X[i4*4+1],X[i4*4+2],X[i4*4+3]};
    float4 zo = {Z[i4*4+0],Z[i4*4+1],Z[i4*4+2],Z[i4*4+3]};
    *(float4*)&phi[base + i4*4] = xo;
    *(float4*)&cc [base + i4*4] = zo;
  }
}

// ---- pass 2: sequential chunk combine per (b,h)
__global__ __launch_bounds__(256) void chunk_state_kernel(
    const float* __restrict__ phi, const float* __restrict__ cc,
    float* __restrict__ sstart)
{
  const int bh = blockIdx.x;
  const int tid = threadIdx.x;
  const int rb = tid >> 4;
  const int cq = tid & 15;
  __shared__ float Sld[64][65];
  __shared__ float Fld[64][68];
  float acc[4][4];
#pragma unroll
  for (int m=0;m<4;m++)
#pragma unroll
    for (int i=0;i<4;i++) acc[m][i] = 0.f;
#pragma unroll
  for (int m=0;m<4;m++){
    float4 z4 = {0.f,0.f,0.f,0.f};
    *(float4*)&Sld[rb+16*m][cq*4] = z4;
  }
  const float* pc = phi + (size_t)bh*NC_*4096;
  float4 pf[4];
#pragma unroll
  for (int p=0;p<4;p++) pf[p] = *(const float4*)&pc[(size_t)p*1024 + tid*4];

  for (int c=0;c<NC_;c++){
    __syncthreads();
#pragma unroll
    for (int p=0;p<4;p++){
      int f = p*1024 + tid*4;
      *(float4*)&Fld[f>>6][f&63] = pf[p];
    }
    if (c+1 < NC_){
#pragma unroll
      for (int p=0;p<4;p++) pf[p] = *(const float4*)&pc[(size_t)(c+1)*4096 + p*1024 + tid*4];
    }
    float na[4][4];
#pragma unroll
    for (int m=0;m<4;m++){
      float4 ci = *(const float4*)&cc[(size_t)(bh*NC_+c)*4096 + (size_t)(rb+16*m)*64 + cq*4];
      na[m][0]=ci.x; na[m][1]=ci.y; na[m][2]=ci.z; na[m][3]=ci.w;
    }
#pragma unroll
    for (int m=0;m<4;m++){
      float4 so = {acc[m][0],acc[m][1],acc[m][2],acc[m][3]};
      *(float4*)&sstart[(size_t)(bh*NC_+c)*4096 + (size_t)(rb+16*m)*64 + cq*4] = so;
    }
    __syncthreads();
#pragma unroll 1
    for (int k0=0;k0<64;k0+=4){
      float4 sr[4];
#pragma unroll
      for (int m=0;m<4;m++) sr[m] = *(const float4*)&Sld[rb+16*m][k0];
      const float4 f0 = *(const float4*)&Fld[k0+0][cq*4];
      const float4 f1 = *(const float4*)&Fld[k0+1][cq*4];
      const float4 f2 = *(const float4*)&Fld[k0+2][cq*4];
      const float4 f3 = *(const float4*)&Fld[k0+3][cq*4];
#pragma unroll
      for (int m=0;m<4;m++){
        na[m][0] = fmaf(sr[m].x, f0.x, na[m][0]); na[m][0] = fmaf(sr[m].y, f1.x, na[m][0]);
        na[m][0] = fmaf(sr[m].z, f2.x, na[m][0]); na[m][0] = fmaf(sr[m].w, f3.x, na[m][0]);
        na[m][1] = fmaf(sr[m].x, f0.y, na[m][1]); na[m][1] = fmaf(sr[m].y, f1.y, na[m][1]);
        na[m][1] = fmaf(sr[m].z, f2.y, na[m][1]); na[m][1] = fmaf(sr[m].w, f3.y, na[m][1]);
        na[m][2] = fmaf(sr[m].x, f0.z, na[m][2]); na[m][2] = fmaf(sr[m].y, f1.z, na[m][2]);
        na[m][2] = fmaf(sr[m].z, f2.z, na[m][2]); na[m][2] = fmaf(sr[m].w, f3.z, na[m][2]);
        na[m][3] = fmaf(sr[m].x, f0.w, na[m][3]); na[m][3] = fmaf(sr[m].y, f1.w, na[m][3]);
        na[m][3] = fmaf(sr[m].z, f2.w, na[m][3]); na[m][3] = fmaf(sr[m].w, f3.w, na[m][3]);
      }
    }
    __syncthreads();
#pragma unroll
    for (int m=0;m<4;m++){
      float4 so = {na[m][0],na[m][1],na[m][2],na[m][3]};
      *(float4*)&Sld[rb+16*m][cq*4] = so;
#pragma unroll
      for (int i=0;i<4;i++) acc[m][i] = na[m][i];
    }
  }
}

// ---- pass 3: per-chunk scan from S_start, emit y (bf16)
__global__ __launch_bounds__(256) void chunk_out_kernel(
    const uint32_t* __restrict__ packed, const float* __restrict__ ratio,
    const float* __restrict__ g, const float* __restrict__ rk,
    const float* __restrict__ sstart, ushort_t* __restrict__ y)
{
  const int blk = blockIdx.x;
  const int c  = blk & (NC_-1);
  const int bh = blk >> 4;
  const int b = bh >> 4, h = bh & 15;
  const int tid = threadIdx.x;
  const int r  = tid >> 2;
  const int qr = tid & 3;
  const int t0 = c * L_;

  __shared__ float ewS[4][N_], zS[4][N_], bS[4][N_], kS[4][N_], qS[4][N_], vS[4][N_], gS[4][N_];
  __shared__ float ratS[4];

  float S[16];
#pragma unroll
  for (int i4=0;i4<4;i4++){
    float4 s4 = *(const float4*)&sstart[(size_t)blk*4096 + (size_t)r*64 + qr*16 + i4*4];
    S[i4*4+0]=s4.x; S[i4*4+1]=s4.y; S[i4*4+2]=s4.z; S[i4*4+3]=s4.w;
  }
  const float sigrk = 1.f/(1.f+__expf(-rk[h*64+r]));

  const int s = tid >> 6, d = tid & 63;
  size_t ap = (((size_t)(b*T_+t0+s))*H_ + h)*64 + d;
  uint32_t pu0 = packed[ap*3], pu1 = packed[ap*3+1], pu2 = packed[ap*3+2];
  float pg = g[(size_t)(b*T_+t0+s)*C_ + h*64 + d];
  float prat = 0.f;
  if (d == 0) prat = ratio[(size_t)(b*T_+t0+s)*H_ + h];

  for (int tg = 0; tg < L_; tg += 4){
    __syncthreads();
    ewS[s][d] = __expf(bf2f(pu0 & 0xffffu));
    zS[s][d]  = bf2f(pu0 >> 16);
    bS[s][d]  = bf2f(pu1 & 0xffffu);
    kS[s][d]  = bf2f(pu1 >> 16);
    qS[s][d]  = bf2f(pu2 & 0xffffu);
    vS[s][d]  = bf2f(pu2 >> 16);
    gS[s][d]  = pg;
    if (d == 0) ratS[s] = prat;
    if (tg + 4 < L_){
      size_t a2 = (((size_t)(b*T_+t0+tg+4+s))*H_ + h)*64 + d;
      pu0 = packed[a2*3]; pu1 = packed[a2*3+1]; pu2 = packed[a2*3+2];
      pg = g[(size_t)(b*T_+t0+tg+4+s)*C_ + h*64 + d];
      if (d == 0) prat = ratio[(size_t)(b*T_+t0+tg+4+s)*H_ + h];
    }
    __syncthreads();
#pragma unroll 1
    for (int ss=0; ss<4; ss++){
      float4 zv[4], ev[4], bv4[4], kv[4], qv[4];
#pragma unroll
      for (int i4=0;i4<4;i4++){
        zv[i4]  = *(const float4*)&zS[ss][qr*16+i4*4];
        ev[i4]  = *(const float4*)&ewS[ss][qr*16+i4*4];
        bv4[i4] = *(const float4*)&bS[ss][qr*16+i4*4];
        kv[i4]  = *(const float4*)&kS[ss][qr*16+i4*4];
        qv[i4]  = *(const float4*)&qS[ss][qr*16+i4*4];
      }
      const float vr = vS[ss][r];
      const float gvr = gS[ss][r];
      const float uv = ratS[ss];
      float a0=0.f,a1=0.f,a2=0.f,a3=0.f;
#pragma unroll
      for (int i4=0;i4<4;i4++){
        const float4 z4 = zv[i4];
        a0 = fmaf(S[i4*4+0], z4.x, a0); a1 = fmaf(S[i4*4+1], z4.y, a1);
        a2 = fmaf(S[i4*4+2], z4.z, a2); a3 = fmaf(S[i4*4+3], z4.w, a3);
      }
      float sa = (a0+a1)+(a2+a3);
      sa += __shfl_xor(sa,1,64); sa += __shfl_xor(sa,2,64);
      float p0=0.f,p1=0.f,p2=0.f,p3=0.f;
#pragma unroll
      for (int i4=0;i4<4;i4++){
        const float4 e4=ev[i4], b4=bv4[i4], k4=kv[i4], q4=qv[i4];
        float t;
        t = fmaf(S[i4*4+0], e4.x, fmaf(sa, b4.x, vr*k4.x)); S[i4*4+0]=t; p0 = fmaf(t, q4.x, p0);
        t = fmaf(S[i4*4+1], e4.y, fmaf(sa, b4.y, vr*k4.y)); S[i4*4+1]=t; p1 = fmaf(t, q4.y, p1);
        t = fmaf(S[i4*4+2], e4.z, fmaf(sa, b4.z, vr*k4.z)); S[i4*4+2]=t; p2 = fmaf(t, q4.z, p2);
        t = fmaf(S[i4*4+3], e4.w, fmaf(sa, b4.w, vr*k4.w)); S[i4*4+3]=t; p3 = fmaf(t, q4.w, p3);
      }
      float o = (p0+p1)+(p2+p3);
      o += __shfl_xor(o,1,64); o += __shfl_xor(o,2,64);
      if (qr == 0){
        y[(size_t)(b*T_+t0+tg+ss)*C_ + h*64 + r] = f2bf((o*0.125f + vr*uv*sigrk)*gvr);
      }
    }
  }
}

extern "C" void kernel_launch(void* const* d_in, const int* in_sizes, int n_in,
                              void* d_out, int out_size, void* d_ws, size_t ws_size,
                              hipStream_t stream)
{
  const float* residual = (const float*)d_in[0];
  const float* x    = (const float*)d_in[1];
  const float* x0   = (const float*)d_in[2];
  const float* dx0  = (const float*)d_in[3];
  const float* Wq   = (const float*)d_in[4];
  const float* Wk   = (const float*)d_in[5];
  const float* Wv   = (const float*)d_in[6];
  const float* Wpr  = (const float*)d_in[7];
  const float* x_q  = (const float*)d_in[8];
  const float* x_k  = (const float*)d_in[9];
  const float* x_v  = (const float*)d_in[10];
  const float* v0   = (const float*)d_in[11];
  const float* w0   = (const float*)d_in[12];
  const float* a0   = (const float*)d_in[13];
  const float* miss = (const float*)d_in[14];
  const float* rk   = (const float*)d_in[15];
  float* out = (float*)d_out;

  char* ws = (char*)d_ws;
  const size_t MB = (size_t)1 << 20;
  float*    q_m    = (float*)(ws + 0*MB);      // 16MB each, q,k,v,vf contiguous
  float*    k_m    = (float*)(ws + 16*MB);
  float*    v_m    = (float*)(ws + 32*MB);
  float*    vf_m   = (float*)(ws + 48*MB);
  ushort_t* delb   = (ushort_t*)(ws + 64*MB);  // 32MB bf16 deltas
  float*    phi    = (float*)(ws + 96*MB);     // 8MB
  float*    cc     = (float*)(ws + 104*MB);    // 8MB
  float*    sstart = (float*)(ws + 112*MB);    // 8MB
  ushort_t* Wpb    = (ushort_t*)(ws + 120*MB); // 2MB
  ushort_t* missT  = (ushort_t*)(ws + 122*MB); // 1MB
  ushort_t* Ab     = (ushort_t*)(ws + 124*MB); // 32MB: Aq,Ak,Av,Axf contiguous
  ushort_t* Xb     = (ushort_t*)(ws + 156*MB); // 8MB
  ushort_t* Wb     = (ushort_t*)(ws + 164*MB); // 8MB: Wq,Wk,Wv,Wv
  uint32_t* packed = (uint32_t*)(ws + 124*MB); // 48MB overlay [124,172) — Ab/Xb/Wb dead by fuse
  float*    g_m    = (float*)(ws + 172*MB);    // 16MB
  float*    ratio  = (float*)(ws + 188*MB);    // 256KB
  ushort_t* yb     = (ushort_t*)(ws + 0*MB);   // 8MB overlay q_m (dead after fuse)

  ushort_t* Aq  = Ab + 0*(size_t)M_*C_;
  ushort_t* Ak  = Ab + 1*(size_t)M_*C_;
  ushort_t* Av  = Ab + 2*(size_t)M_*C_;
  ushort_t* Axf = Ab + 3*(size_t)M_*C_;

  dim3 blk(256);
  prep_act<<<M_*C_/4/256, blk, 0, stream>>>(x, x0, dx0, x_q, x_k, x_v, Aq, Ak, Av, Axf, Xb);
  prep_w<<<dim3(C_*C_/4/256, 5), blk, 0, stream>>>(Wq, Wk, Wv, Wpr, Wb, Wpb);
  prep_missT<<<4096/64, blk, 0, stream>>>(miss, missT);
  // 4 main GEMMs batched: z selects (Aq,Wq)->q_m, (Ak,Wk)->k_m, (Av,Wv)->v_m, (Axf,Wv)->vf_m
  mfma_gemm<<<dim3(C_/128, M_/128, 4), blk, 0, stream>>>(
      Ab, C_, (int64_t)M_*C_, Wb, C_, (int64_t)C_*C_,
      q_m, C_, (int64_t)M_*C_, 0, nullptr, C_);
  // deltas = x[:, :128] @ miss  -> bf16 [M_ x 4096]
  mfma_gemm<<<dim3(4*C_/128, M_/128, 1), blk, 0, stream>>>(
      Xb, C_, 0, missT, 128, 0, delb, 4*C_, 0, 1, nullptr, 128);
  fuse_kernel<<<M_*H_/4, blk, 0, stream>>>(q_m, k_m, v_m, vf_m, delb, x, w0, v0, a0, packed, g_m, ratio);
  chunk_phi_kernel<<<B_*H_*NC_, blk, 0, stream>>>(packed, phi, cc);
  chunk_state_kernel<<<B_*H_, blk, 0, stream>>>(phi, cc, sstart);
  chunk_out_kernel<<<B_*H_*NC_, blk, 0, stream>>>(packed, ratio, g_m, rk, sstart, yb);
  // out = residual + y @ Wproj^T
  mfma_gemm<<<dim3(C_/128, M_/128, 1), blk, 0, stream>>>(
      yb, C_, 0, Wpb, C_, 0, out, C_, 0, 0, residual, C_);
}